// Round 2
// baseline (3323.656 us; speedup 1.0000x reference)
//
#include <hip/hip_runtime.h>
#include <math.h>

#define EMB 64

// monotone float<->unsigned encoding for atomicMax on float
__device__ __forceinline__ unsigned f2enc(float f) {
    unsigned u = __float_as_uint(f);
    return (u & 0x80000000u) ? ~u : (u | 0x80000000u);
}
__device__ __forceinline__ float enc2f(unsigned e) {
    unsigned u = (e & 0x80000000u) ? (e & 0x7fffffffu) : ~e;
    return __uint_as_float(u);
}

// --- init: agg = entity_emb, kg(=d_out) = 0 ---
__global__ void init_kernel(float* __restrict__ agg, float* __restrict__ kg,
                            const float* __restrict__ ent, int n) {
    int i = blockIdx.x * blockDim.x + threadIdx.x;
    if (i < n) { agg[i] = ent[i]; kg[i] = 0.0f; }
}

// --- degree count (hop-invariant) ---
__global__ void cnt_kernel(float* __restrict__ cnt, const int* __restrict__ head, int E) {
    int e = blockIdx.x * blockDim.x + threadIdx.x;
    if (e < E) atomicAdd(&cnt[head[e]], 1.0f);
}

// --- Q = agg @ q_w : one wave per entity row, W staged in LDS ---
__global__ void qproj_kernel(float* __restrict__ Q, const float* __restrict__ agg,
                             const float* __restrict__ qw, int N) {
    __shared__ float Wl[EMB * EMB];
    for (int i = threadIdx.x; i < EMB * EMB; i += blockDim.x) Wl[i] = qw[i];
    __syncthreads();
    int lane = threadIdx.x & 63;
    int wid = threadIdx.x >> 6;
    int row = blockIdx.x * (blockDim.x >> 6) + wid;
    if (row >= N) return;
    float xv = agg[(size_t)row * EMB + lane];
    float acc = 0.0f;
#pragma unroll
    for (int i = 0; i < EMB; ++i) acc += __shfl(xv, i, 64) * Wl[i * EMB + lane];
    Q[(size_t)row * EMB + lane] = acc;
}

// --- per-edge attention score: att[e] = dot(Q[h], tanh((rel ⊙ agg[t]) @ k_w)) ---
__global__ void att_kernel(float* __restrict__ att, unsigned* __restrict__ smax,
                           const float* __restrict__ agg, const float* __restrict__ Q,
                           const float* __restrict__ eemb,
                           const float* __restrict__ kw,
                           const int* __restrict__ head, const int* __restrict__ tail,
                           const int* __restrict__ etype, int E) {
    __shared__ float Kl[EMB * EMB];
    for (int i = threadIdx.x; i < EMB * EMB; i += blockDim.x) Kl[i] = kw[i];
    __syncthreads();
    int lane = threadIdx.x & 63;
    int wid = threadIdx.x >> 6;
    int e = blockIdx.x * (blockDim.x >> 6) + wid;
    if (e >= E) return;
    int h = head[e], t = tail[e], r = etype[e];
    float xv = eemb[r * EMB + lane] * agg[(size_t)t * EMB + lane];
    float acc = 0.0f;
#pragma unroll
    for (int i = 0; i < EMB; ++i) acc += __shfl(xv, i, 64) * Kl[i * EMB + lane];
    float y = tanhf(acc);
    float p = Q[(size_t)h * EMB + lane] * y;
#pragma unroll
    for (int o = 32; o > 0; o >>= 1) p += __shfl_xor(p, o, 64);
    if (lane == 0) {
        att[e] = p;
        atomicMax(&smax[h], f2enc(p));
    }
}

// --- softmax numerator (in-place att -> exp) + denominator ---
__global__ void softmax_kernel(float* __restrict__ att, float* __restrict__ denom,
                               const unsigned* __restrict__ smax,
                               const int* __restrict__ head, int E) {
    int e = blockIdx.x * blockDim.x + threadIdx.x;
    if (e >= E) return;
    int h = head[e];
    float m = enc2f(smax[h]);
    float v = expf(att[e] - m);
    att[e] = v;
    atomicAdd(&denom[h], v);
}

// --- weighted message scatter: s[h] += w * rel ⊙ agg[t] ---
__global__ void scatter_kernel(float* __restrict__ s, const float* __restrict__ ev,
                               const float* __restrict__ denom, const float* __restrict__ agg,
                               const float* __restrict__ eemb,
                               const int* __restrict__ head, const int* __restrict__ tail,
                               const int* __restrict__ etype, int E) {
    int lane = threadIdx.x & 63;
    int wid = threadIdx.x >> 6;
    int e = blockIdx.x * (blockDim.x >> 6) + wid;
    if (e >= E) return;
    int h = head[e], t = tail[e], r = etype[e];
    float w = ev[e] / denom[h];
    float val = w * eemb[r * EMB + lane] * agg[(size_t)t * EMB + lane];
    atomicAdd(&s[(size_t)h * EMB + lane], val);
}

// --- agg = l2norm(s / max(cnt,1)); kg += agg + entity_emb ---
__global__ void finalize_kernel(float* __restrict__ agg, float* __restrict__ kg,
                                const float* __restrict__ s, const float* __restrict__ cnt,
                                const float* __restrict__ ent, int N) {
    int lane = threadIdx.x & 63;
    int wid = threadIdx.x >> 6;
    int n = blockIdx.x * (blockDim.x >> 6) + wid;
    if (n >= N) return;
    float c = fmaxf(cnt[n], 1.0f);
    float v = s[(size_t)n * EMB + lane] / c;
    float ss = v * v;
#pragma unroll
    for (int o = 32; o > 0; o >>= 1) ss += __shfl_xor(ss, o, 64);
    float nrm = sqrtf(ss);
    v = v / fmaxf(nrm, 1e-12f);
    agg[(size_t)n * EMB + lane] = v;
    kg[(size_t)n * EMB + lane] += v + ent[(size_t)n * EMB + lane];
}

extern "C" void kernel_launch(void* const* d_in, const int* in_sizes, int n_in,
                              void* d_out, int out_size, void* d_ws, size_t ws_size,
                              hipStream_t stream) {
    const float* ent  = (const float*)d_in[0];
    const float* eemb = (const float*)d_in[1];
    const float* qw   = (const float*)d_in[2];
    const float* kw   = (const float*)d_in[3];
    const int* eidx  = (const int*)d_in[4];
    const int* etype = (const int*)d_in[5];

    const int N = in_sizes[0] / EMB;
    const int E = in_sizes[5];
    const int* head = eidx;
    const int* tail = eidx + E;

    float* kg = (float*)d_out;              // N*EMB accumulator lives in d_out

    // workspace layout (floats)
    float* agg   = (float*)d_ws;            // N*EMB
    float* Qb    = agg  + (size_t)N * EMB;  // N*EMB
    float* sbuf  = Qb   + (size_t)N * EMB;  // N*EMB
    float* att   = sbuf + (size_t)N * EMB;  // E (reused as ev in-place)
    float* denom = att  + E;                // N
    unsigned* smax = (unsigned*)(denom + N);// N
    float* cnt   = (float*)(smax + N);      // N

    const int NT = 256;
    const int WPB = NT / 64;

    hipMemsetAsync(cnt, 0, (size_t)N * 4, stream);
    init_kernel<<<(N * EMB + NT - 1) / NT, NT, 0, stream>>>(agg, kg, ent, N * EMB);
    cnt_kernel<<<(E + NT - 1) / NT, NT, 0, stream>>>(cnt, head, E);

    for (int hop = 0; hop < 2; ++hop) {
        hipMemsetAsync(sbuf, 0, (size_t)N * EMB * 4, stream);
        hipMemsetAsync(denom, 0, (size_t)N * 4, stream);
        hipMemsetAsync(smax, 0, (size_t)N * 4, stream);

        qproj_kernel<<<(N + WPB - 1) / WPB, NT, 0, stream>>>(Qb, agg, qw, N);
        att_kernel<<<(E + WPB - 1) / WPB, NT, 0, stream>>>(att, smax, agg, Qb, eemb, kw,
                                                           head, tail, etype, E);
        softmax_kernel<<<(E + NT - 1) / NT, NT, 0, stream>>>(att, denom, smax, head, E);
        scatter_kernel<<<(E + WPB - 1) / WPB, NT, 0, stream>>>(sbuf, att, denom, agg, eemb,
                                                               head, tail, etype, E);
        finalize_kernel<<<(N + WPB - 1) / WPB, NT, 0, stream>>>(agg, kg, sbuf, cnt, ent, N);
    }
}

// Round 3
// 964.394 us; speedup vs baseline: 3.4464x; 3.4464x over previous
//
#include <hip/hip_runtime.h>
#include <math.h>

#define EMB 64

typedef short bf16x8 __attribute__((ext_vector_type(8)));
typedef float f32x4 __attribute__((ext_vector_type(4)));

__device__ __forceinline__ short f2bf(float f) {
    unsigned u = __float_as_uint(f);
    u += 0x7FFFu + ((u >> 16) & 1u);   // RNE
    return (short)(u >> 16);
}

// monotone float<->unsigned encoding for atomicMax on float
__device__ __forceinline__ unsigned f2enc(float f) {
    unsigned u = __float_as_uint(f);
    return (u & 0x80000000u) ? ~u : (u | 0x80000000u);
}
__device__ __forceinline__ float enc2f(unsigned e) {
    unsigned u = (e & 0x80000000u) ? (e & 0x7fffffffu) : ~e;
    return __uint_as_float(u);
}

// --- init: agg = entity_emb, kg(=d_out) = 0 ---
__global__ void init_kernel(float* __restrict__ agg, float* __restrict__ kg,
                            const float* __restrict__ ent, int n) {
    int i = blockIdx.x * blockDim.x + threadIdx.x;
    if (i < n) { agg[i] = ent[i]; kg[i] = 0.0f; }
}

// --- degree count (hop-invariant) ---
__global__ void cnt_kernel(float* __restrict__ cnt, const int* __restrict__ head, int E) {
    int e = blockIdx.x * blockDim.x + threadIdx.x;
    if (e < E) atomicAdd(&cnt[head[e]], 1.0f);
}

// Build B fragments (2 k-halves x 4 n-tiles) from a 64x64 fp32 row-major matrix.
// Layout per 16x16x32 MFMA: lane holds B[k=(lane>>4)*8+j][n=lane&15] (+tile offsets).
__device__ __forceinline__ void build_bfrags(bf16x8 bfrag[2][4], const float* __restrict__ W,
                                             int lane) {
    int koff = (lane >> 4) * 8;
    int n = lane & 15;
#pragma unroll
    for (int kh = 0; kh < 2; ++kh)
#pragma unroll
        for (int nt = 0; nt < 4; ++nt) {
            bf16x8 b;
#pragma unroll
            for (int j = 0; j < 8; ++j)
                b[j] = f2bf(W[(kh * 32 + koff + j) * EMB + nt * 16 + n]);
            bfrag[kh][nt] = b;
        }
}

// --- Q = agg @ q_w via MFMA: 16 rows per wave-tile ---
__global__ void qproj_mfma_kernel(float* __restrict__ Qout, const float* __restrict__ agg,
                                  const float* __restrict__ qw, int N) {
    int lane = threadIdx.x & 63;
    int gwave = blockIdx.x * (blockDim.x >> 6) + (threadIdx.x >> 6);
    int nwaves = gridDim.x * (blockDim.x >> 6);
    int row = lane & 15;
    int g = lane >> 4;
    int koff = g * 8;

    bf16x8 bfrag[2][4];
    build_bfrags(bfrag, qw, lane);

    int ntiles = (N + 15) >> 4;
    for (int tile = gwave; tile < ntiles; tile += nwaves) {
        int rIdx = min(tile * 16 + row, N - 1);
        const float* ag = agg + (size_t)rIdx * EMB;
        bf16x8 a0, a1;
#pragma unroll
        for (int j = 0; j < 8; ++j) a0[j] = f2bf(ag[koff + j]);
#pragma unroll
        for (int j = 0; j < 8; ++j) a1[j] = f2bf(ag[32 + koff + j]);
#pragma unroll
        for (int nt = 0; nt < 4; ++nt) {
            f32x4 acc = {0.f, 0.f, 0.f, 0.f};
            acc = __builtin_amdgcn_mfma_f32_16x16x32_bf16(a0, bfrag[0][nt], acc, 0, 0, 0);
            acc = __builtin_amdgcn_mfma_f32_16x16x32_bf16(a1, bfrag[1][nt], acc, 0, 0, 0);
#pragma unroll
            for (int reg = 0; reg < 4; ++reg) {
                int n2 = tile * 16 + g * 4 + reg;
                if (n2 < N) Qout[(size_t)n2 * EMB + nt * 16 + (lane & 15)] = acc[reg];
            }
        }
    }
}

// --- per-edge attention via MFMA: att[e] = Q[h] . tanh((rel ⊙ agg[t]) @ k_w) ---
__global__ void att_mfma_kernel(float* __restrict__ att, unsigned* __restrict__ smax,
                                const float* __restrict__ agg, const float* __restrict__ Q,
                                const float* __restrict__ eemb, const float* __restrict__ kw,
                                const int* __restrict__ head, const int* __restrict__ tail,
                                const int* __restrict__ etype, int E) {
    int lane = threadIdx.x & 63;
    int gwave = blockIdx.x * (blockDim.x >> 6) + (threadIdx.x >> 6);
    int nwaves = gridDim.x * (blockDim.x >> 6);
    int row = lane & 15;
    int g = lane >> 4;
    int koff = g * 8;

    bf16x8 bfrag[2][4];
    build_bfrags(bfrag, kw, lane);

    int ntiles = (E + 15) >> 4;
    for (int tile = gwave; tile < ntiles; tile += nwaves) {
        int eld = min(tile * 16 + row, E - 1);
        int t = tail[eld], h = head[eld], r = etype[eld];
        const float* ag = agg + (size_t)t * EMB;
        const float* rl = eemb + r * EMB;
        bf16x8 a0, a1;
#pragma unroll
        for (int j = 0; j < 8; ++j) a0[j] = f2bf(rl[koff + j] * ag[koff + j]);
#pragma unroll
        for (int j = 0; j < 8; ++j) a1[j] = f2bf(rl[32 + koff + j] * ag[32 + koff + j]);

        float sums0 = 0.f, sums1 = 0.f, sums2 = 0.f, sums3 = 0.f;
#pragma unroll
        for (int nt = 0; nt < 4; ++nt) {
            f32x4 acc = {0.f, 0.f, 0.f, 0.f};
            acc = __builtin_amdgcn_mfma_f32_16x16x32_bf16(a0, bfrag[0][nt], acc, 0, 0, 0);
            acc = __builtin_amdgcn_mfma_f32_16x16x32_bf16(a1, bfrag[1][nt], acc, 0, 0, 0);
#pragma unroll
            for (int reg = 0; reg < 4; ++reg) {
                int row2 = g * 4 + reg;
                int h2 = __shfl(h, row2, 64);      // head of edge row2 (from lane row2)
                float q = Q[(size_t)h2 * EMB + nt * 16 + (lane & 15)];
                float v = q * tanhf(acc[reg]);
                if (reg == 0) sums0 += v;
                else if (reg == 1) sums1 += v;
                else if (reg == 2) sums2 += v;
                else sums3 += v;
            }
        }
        // reduce over the 16 lanes of group g (they cover the 64 cols)
#pragma unroll
        for (int m = 1; m <= 8; m <<= 1) {
            sums0 += __shfl_xor(sums0, m, 64);
            sums1 += __shfl_xor(sums1, m, 64);
            sums2 += __shfl_xor(sums2, m, 64);
            sums3 += __shfl_xor(sums3, m, 64);
        }
        // write att for rows g*4+reg; lane (lane&15)==reg in each group writes
#pragma unroll
        for (int reg = 0; reg < 4; ++reg) {
            int row2 = g * 4 + reg;
            int h2 = __shfl(h, row2, 64);          // all lanes execute (no exec-mask hazard)
            int e2 = tile * 16 + row2;
            float v = (reg == 0) ? sums0 : (reg == 1) ? sums1 : (reg == 2) ? sums2 : sums3;
            if ((lane & 15) == reg && e2 < E) {
                att[e2] = v;
                atomicMax(&smax[h2], f2enc(v));
            }
        }
    }
}

// --- softmax numerator (in-place att -> exp) + denominator ---
__global__ void softmax_kernel(float* __restrict__ att, float* __restrict__ denom,
                               const unsigned* __restrict__ smax,
                               const int* __restrict__ head, int E) {
    int e = blockIdx.x * blockDim.x + threadIdx.x;
    if (e >= E) return;
    int h = head[e];
    float m = enc2f(smax[h]);
    float v = expf(att[e] - m);
    att[e] = v;
    atomicAdd(&denom[h], v);
}

// --- weighted message scatter: s[h] += w * rel ⊙ agg[t] ---
__global__ void scatter_kernel(float* __restrict__ s, const float* __restrict__ ev,
                               const float* __restrict__ denom, const float* __restrict__ agg,
                               const float* __restrict__ eemb,
                               const int* __restrict__ head, const int* __restrict__ tail,
                               const int* __restrict__ etype, int E) {
    int lane = threadIdx.x & 63;
    int wid = threadIdx.x >> 6;
    int e = blockIdx.x * (blockDim.x >> 6) + wid;
    if (e >= E) return;
    int h = head[e], t = tail[e], r = etype[e];
    float w = ev[e] / denom[h];
    float val = w * eemb[r * EMB + lane] * agg[(size_t)t * EMB + lane];
    atomicAdd(&s[(size_t)h * EMB + lane], val);
}

// --- agg = l2norm(s / max(cnt,1)); kg += agg + entity_emb ---
__global__ void finalize_kernel(float* __restrict__ agg, float* __restrict__ kg,
                                const float* __restrict__ s, const float* __restrict__ cnt,
                                const float* __restrict__ ent, int N) {
    int lane = threadIdx.x & 63;
    int wid = threadIdx.x >> 6;
    int n = blockIdx.x * (blockDim.x >> 6) + wid;
    if (n >= N) return;
    float c = fmaxf(cnt[n], 1.0f);
    float v = s[(size_t)n * EMB + lane] / c;
    float ss = v * v;
#pragma unroll
    for (int o = 32; o > 0; o >>= 1) ss += __shfl_xor(ss, o, 64);
    float nrm = sqrtf(ss);
    v = v / fmaxf(nrm, 1e-12f);
    agg[(size_t)n * EMB + lane] = v;
    kg[(size_t)n * EMB + lane] += v + ent[(size_t)n * EMB + lane];
}

extern "C" void kernel_launch(void* const* d_in, const int* in_sizes, int n_in,
                              void* d_out, int out_size, void* d_ws, size_t ws_size,
                              hipStream_t stream) {
    const float* ent  = (const float*)d_in[0];
    const float* eemb = (const float*)d_in[1];
    const float* qw   = (const float*)d_in[2];
    const float* kw   = (const float*)d_in[3];
    const int* eidx  = (const int*)d_in[4];
    const int* etype = (const int*)d_in[5];

    const int N = in_sizes[0] / EMB;
    const int E = in_sizes[5];
    const int* head = eidx;
    const int* tail = eidx + E;

    float* kg = (float*)d_out;              // N*EMB accumulator lives in d_out

    // workspace layout (floats)
    float* agg   = (float*)d_ws;            // N*EMB
    float* Qb    = agg  + (size_t)N * EMB;  // N*EMB
    float* sbuf  = Qb   + (size_t)N * EMB;  // N*EMB
    float* att   = sbuf + (size_t)N * EMB;  // E (reused as ev in-place)
    float* denom = att  + E;                // N
    unsigned* smax = (unsigned*)(denom + N);// N
    float* cnt   = (float*)(smax + N);      // N

    const int NT = 256;
    const int WPB = NT / 64;

    hipMemsetAsync(cnt, 0, (size_t)N * 4, stream);
    init_kernel<<<(N * EMB + NT - 1) / NT, NT, 0, stream>>>(agg, kg, ent, N * EMB);
    cnt_kernel<<<(E + NT - 1) / NT, NT, 0, stream>>>(cnt, head, E);

    for (int hop = 0; hop < 2; ++hop) {
        hipMemsetAsync(sbuf, 0, (size_t)N * EMB * 4, stream);
        hipMemsetAsync(denom, 0, (size_t)N * 4, stream);
        hipMemsetAsync(smax, 0, (size_t)N * 4, stream);

        qproj_mfma_kernel<<<512, NT, 0, stream>>>(Qb, agg, qw, N);
        att_mfma_kernel<<<1024, NT, 0, stream>>>(att, smax, agg, Qb, eemb, kw,
                                                 head, tail, etype, E);
        softmax_kernel<<<(E + NT - 1) / NT, NT, 0, stream>>>(att, denom, smax, head, E);
        scatter_kernel<<<(E + WPB - 1) / WPB, NT, 0, stream>>>(sbuf, att, denom, agg, eemb,
                                                               head, tail, etype, E);
        finalize_kernel<<<(N + WPB - 1) / WPB, NT, 0, stream>>>(agg, kg, sbuf, cnt, ent, N);
    }
}

// Round 4
// 755.601 us; speedup vs baseline: 4.3987x; 1.2763x over previous
//
#include <hip/hip_runtime.h>
#include <math.h>

#define EMB 64

typedef short bf16x8 __attribute__((ext_vector_type(8)));
typedef float f32x4 __attribute__((ext_vector_type(4)));

__device__ __forceinline__ short f2bf(float f) {
    unsigned u = __float_as_uint(f);
    u += 0x7FFFu + ((u >> 16) & 1u);   // RNE
    return (short)(u >> 16);
}

// --- init: agg = entity_emb, kg(=d_out) = 0 ---
__global__ void init_kernel(float* __restrict__ agg, float* __restrict__ kg,
                            const float* __restrict__ ent, int n) {
    int i = blockIdx.x * blockDim.x + threadIdx.x;
    if (i < n) { agg[i] = ent[i]; kg[i] = 0.0f; }
}

// ============ one-time CSR build (counting sort by head) ============

__global__ void hist_kernel(int* __restrict__ deg, const int* __restrict__ head, int E) {
    int e = blockIdx.x * blockDim.x + threadIdx.x;
    if (e < E) atomicAdd(&deg[head[e]], 1);
}

// block-level exclusive scan: 1024 elements per block (256 thr x 4)
__global__ void scan_blocks(const int* __restrict__ deg, int* __restrict__ excl,
                            int* __restrict__ bsum, int n) {
    __shared__ int wsum[4];
    int base = blockIdx.x * 1024;
    int t = threadIdx.x;
    int lane = t & 63, wid = t >> 6;
    int idx = base + t * 4;
    int v0 = (idx + 0 < n) ? deg[idx + 0] : 0;
    int v1 = (idx + 1 < n) ? deg[idx + 1] : 0;
    int v2 = (idx + 2 < n) ? deg[idx + 2] : 0;
    int v3 = (idx + 3 < n) ? deg[idx + 3] : 0;
    int s0 = v0, s1 = s0 + v1, s2 = s1 + v2, s3 = s2 + v3;
    int tsum = s3;
    int inc = tsum;
#pragma unroll
    for (int o = 1; o < 64; o <<= 1) { int u = __shfl_up(inc, o, 64); if (lane >= o) inc += u; }
    if (lane == 63) wsum[wid] = inc;
    __syncthreads();
    int woff = 0;
#pragma unroll
    for (int w = 0; w < 4; ++w) if (w < wid) woff += wsum[w];
    int texcl = woff + inc - tsum;
    if (idx + 0 < n) excl[idx + 0] = texcl;
    if (idx + 1 < n) excl[idx + 1] = texcl + s0;
    if (idx + 2 < n) excl[idx + 2] = texcl + s1;
    if (idx + 3 < n) excl[idx + 3] = texcl + s2;
    if (t == 255) bsum[blockIdx.x] = woff + inc;
}

__global__ void scan_sums(int* __restrict__ bsum, int* __restrict__ excl, int nb, int n, int E) {
    int acc = 0;
    for (int b = 0; b < nb; ++b) { int v = bsum[b]; bsum[b] = acc; acc += v; }
    excl[n] = E;
}

__global__ void scan_add(int* __restrict__ excl, const int* __restrict__ bsum, int n) {
    int i = blockIdx.x * blockDim.x + threadIdx.x;
    if (i < n) excl[i] += bsum[i >> 10];
}

__global__ void sort_scatter(const int* __restrict__ head, const int* __restrict__ tail,
                             const int* __restrict__ etype, const int* __restrict__ offsets,
                             int* __restrict__ cursor, int* __restrict__ shead,
                             int* __restrict__ stail, int* __restrict__ setype, int E) {
    int e = blockIdx.x * blockDim.x + threadIdx.x;
    if (e >= E) return;
    int h = head[e];
    int pos = offsets[h] + atomicAdd(&cursor[h], 1);
    shead[pos] = h;
    stail[pos] = tail[e];
    setype[pos] = etype[e];
}

// ============ per-hop kernels ============

// Build B fragments (2 k-halves x 4 n-tiles) from a 64x64 fp32 row-major matrix.
__device__ __forceinline__ void build_bfrags(bf16x8 bfrag[2][4], const float* __restrict__ W,
                                             int lane) {
    int koff = (lane >> 4) * 8;
    int n = lane & 15;
#pragma unroll
    for (int kh = 0; kh < 2; ++kh)
#pragma unroll
        for (int nt = 0; nt < 4; ++nt) {
            bf16x8 b;
#pragma unroll
            for (int j = 0; j < 8; ++j)
                b[j] = f2bf(W[(kh * 32 + koff + j) * EMB + nt * 16 + n]);
            bfrag[kh][nt] = b;
        }
}

// --- Q = agg @ q_w via MFMA: 16 rows per wave-tile ---
__global__ void qproj_mfma_kernel(float* __restrict__ Qout, const float* __restrict__ agg,
                                  const float* __restrict__ qw, int N) {
    int lane = threadIdx.x & 63;
    int gwave = blockIdx.x * (blockDim.x >> 6) + (threadIdx.x >> 6);
    int nwaves = gridDim.x * (blockDim.x >> 6);
    int row = lane & 15;
    int g = lane >> 4;
    int koff = g * 8;

    bf16x8 bfrag[2][4];
    build_bfrags(bfrag, qw, lane);

    int ntiles = (N + 15) >> 4;
    for (int tile = gwave; tile < ntiles; tile += nwaves) {
        int rIdx = min(tile * 16 + row, N - 1);
        const float* ag = agg + (size_t)rIdx * EMB;
        bf16x8 a0, a1;
#pragma unroll
        for (int j = 0; j < 8; ++j) a0[j] = f2bf(ag[koff + j]);
#pragma unroll
        for (int j = 0; j < 8; ++j) a1[j] = f2bf(ag[32 + koff + j]);
#pragma unroll
        for (int nt = 0; nt < 4; ++nt) {
            f32x4 acc = {0.f, 0.f, 0.f, 0.f};
            acc = __builtin_amdgcn_mfma_f32_16x16x32_bf16(a0, bfrag[0][nt], acc, 0, 0, 0);
            acc = __builtin_amdgcn_mfma_f32_16x16x32_bf16(a1, bfrag[1][nt], acc, 0, 0, 0);
#pragma unroll
            for (int reg = 0; reg < 4; ++reg) {
                int n2 = tile * 16 + g * 4 + reg;
                if (n2 < N) Qout[(size_t)n2 * EMB + nt * 16 + (lane & 15)] = acc[reg];
            }
        }
    }
}

// --- per-edge attention via MFMA over SORTED edges ---
__global__ void att_mfma_kernel(float* __restrict__ att,
                                const float* __restrict__ agg, const float* __restrict__ Q,
                                const float* __restrict__ eemb, const float* __restrict__ kw,
                                const int* __restrict__ shead, const int* __restrict__ stail,
                                const int* __restrict__ setype, int E) {
    int lane = threadIdx.x & 63;
    int gwave = blockIdx.x * (blockDim.x >> 6) + (threadIdx.x >> 6);
    int nwaves = gridDim.x * (blockDim.x >> 6);
    int row = lane & 15;
    int g = lane >> 4;
    int koff = g * 8;

    bf16x8 bfrag[2][4];
    build_bfrags(bfrag, kw, lane);

    int ntiles = (E + 15) >> 4;
    for (int tile = gwave; tile < ntiles; tile += nwaves) {
        int eld = min(tile * 16 + row, E - 1);
        int t = stail[eld], h = shead[eld], r = setype[eld];
        const float* ag = agg + (size_t)t * EMB;
        const float* rl = eemb + r * EMB;
        bf16x8 a0, a1;
#pragma unroll
        for (int j = 0; j < 8; ++j) a0[j] = f2bf(rl[koff + j] * ag[koff + j]);
#pragma unroll
        for (int j = 0; j < 8; ++j) a1[j] = f2bf(rl[32 + koff + j] * ag[32 + koff + j]);

        float sums0 = 0.f, sums1 = 0.f, sums2 = 0.f, sums3 = 0.f;
#pragma unroll
        for (int nt = 0; nt < 4; ++nt) {
            f32x4 acc = {0.f, 0.f, 0.f, 0.f};
            acc = __builtin_amdgcn_mfma_f32_16x16x32_bf16(a0, bfrag[0][nt], acc, 0, 0, 0);
            acc = __builtin_amdgcn_mfma_f32_16x16x32_bf16(a1, bfrag[1][nt], acc, 0, 0, 0);
#pragma unroll
            for (int reg = 0; reg < 4; ++reg) {
                int row2 = g * 4 + reg;
                int h2 = __shfl(h, row2, 64);
                float q = Q[(size_t)h2 * EMB + nt * 16 + (lane & 15)];
                float v = q * tanhf(acc[reg]);
                if (reg == 0) sums0 += v;
                else if (reg == 1) sums1 += v;
                else if (reg == 2) sums2 += v;
                else sums3 += v;
            }
        }
#pragma unroll
        for (int m = 1; m <= 8; m <<= 1) {
            sums0 += __shfl_xor(sums0, m, 64);
            sums1 += __shfl_xor(sums1, m, 64);
            sums2 += __shfl_xor(sums2, m, 64);
            sums3 += __shfl_xor(sums3, m, 64);
        }
#pragma unroll
        for (int reg = 0; reg < 4; ++reg) {
            int row2 = g * 4 + reg;
            int e2 = tile * 16 + row2;
            float v = (reg == 0) ? sums0 : (reg == 1) ? sums1 : (reg == 2) ? sums2 : sums3;
            if ((lane & 15) == reg && e2 < E) att[e2] = v;
        }
    }
}

// --- fused per-head softmax + weighted aggregate + mean + l2norm + residual ---
// one wave per head; edges contiguous in sorted order
__global__ void head_agg_kernel(float* __restrict__ aggNew, float* __restrict__ kg,
                                const float* __restrict__ att, const float* __restrict__ aggOld,
                                const float* __restrict__ eemb, const float* __restrict__ ent,
                                const int* __restrict__ offsets, const int* __restrict__ stail,
                                const int* __restrict__ setype, int N) {
    int lane = threadIdx.x & 63;
    int h = blockIdx.x * (blockDim.x >> 6) + (threadIdx.x >> 6);
    if (h >= N) return;
    int beg = offsets[h], end = offsets[h + 1];

    float m = -3.4e38f;
    for (int e = beg; e < end; ++e) m = fmaxf(m, att[e]);
    float ssum = 0.f;
    for (int e = beg; e < end; ++e) ssum += expf(att[e] - m);
    float inv = 1.0f / ssum;

    float acc = 0.f;
    for (int e = beg; e < end; ++e) {
        float w = expf(att[e] - m) * inv;
        int t = stail[e], r = setype[e];
        acc += w * eemb[r * EMB + lane] * aggOld[(size_t)t * EMB + lane];
    }

    float c = (float)max(end - beg, 1);
    float v = acc / c;
    float ss = v * v;
#pragma unroll
    for (int o = 32; o > 0; o >>= 1) ss += __shfl_xor(ss, o, 64);
    float nrm = sqrtf(ss);
    v = v / fmaxf(nrm, 1e-12f);
    aggNew[(size_t)h * EMB + lane] = v;
    kg[(size_t)h * EMB + lane] += v + ent[(size_t)h * EMB + lane];
}

extern "C" void kernel_launch(void* const* d_in, const int* in_sizes, int n_in,
                              void* d_out, int out_size, void* d_ws, size_t ws_size,
                              hipStream_t stream) {
    const float* ent  = (const float*)d_in[0];
    const float* eemb = (const float*)d_in[1];
    const float* qw   = (const float*)d_in[2];
    const float* kw   = (const float*)d_in[3];
    const int* eidx  = (const int*)d_in[4];
    const int* etype = (const int*)d_in[5];

    const int N = in_sizes[0] / EMB;
    const int E = in_sizes[5];
    const int* head = eidx;
    const int* tail = eidx + E;

    float* kg = (float*)d_out;

    // workspace layout
    float* agg_a = (float*)d_ws;                 // N*EMB
    float* agg_b = agg_a + (size_t)N * EMB;      // N*EMB
    float* Qb    = agg_b + (size_t)N * EMB;      // N*EMB
    float* att   = Qb    + (size_t)N * EMB;      // E
    int* offsets = (int*)(att + E);              // N+1
    int* deg     = offsets + (N + 1);            // N
    int* cursor  = deg + N;                      // N
    int* bsum    = cursor + N;                   // up to 1024
    int* shead   = bsum + 1024;                  // E
    int* stail   = shead + E;                    // E
    int* setype  = stail + E;                    // E

    const int NT = 256;
    const int WPB = NT / 64;
    const int nb = (N + 1023) / 1024;

    // one-time: init + CSR build
    init_kernel<<<(N * EMB + NT - 1) / NT, NT, 0, stream>>>(agg_a, kg, ent, N * EMB);
    hipMemsetAsync(deg, 0, (size_t)N * 4, stream);
    hipMemsetAsync(cursor, 0, (size_t)N * 4, stream);
    hist_kernel<<<(E + NT - 1) / NT, NT, 0, stream>>>(deg, head, E);
    scan_blocks<<<nb, NT, 0, stream>>>(deg, offsets, bsum, N);
    scan_sums<<<1, 1, 0, stream>>>(bsum, offsets, nb, N, E);
    scan_add<<<(N + NT - 1) / NT, NT, 0, stream>>>(offsets, bsum, N);
    sort_scatter<<<(E + NT - 1) / NT, NT, 0, stream>>>(head, tail, etype, offsets, cursor,
                                                       shead, stail, setype, E);

    float* cur = agg_a;
    float* nxt = agg_b;
    for (int hop = 0; hop < 2; ++hop) {
        qproj_mfma_kernel<<<512, NT, 0, stream>>>(Qb, cur, qw, N);
        att_mfma_kernel<<<1024, NT, 0, stream>>>(att, cur, Qb, eemb, kw,
                                                 shead, stail, setype, E);
        head_agg_kernel<<<(N + WPB - 1) / WPB, NT, 0, stream>>>(nxt, kg, att, cur, eemb, ent,
                                                                offsets, stail, setype, N);
        float* tmp = cur; cur = nxt; nxt = tmp;
    }
}

// Round 5
// 603.181 us; speedup vs baseline: 5.5102x; 1.2527x over previous
//
#include <hip/hip_runtime.h>
#include <math.h>

#define EMB 64
#define MAXREL 32

typedef short bf16x8 __attribute__((ext_vector_type(8)));
typedef float f32x4 __attribute__((ext_vector_type(4)));

__device__ __forceinline__ short f2bf(float f) {
    unsigned u = __float_as_uint(f);
    u += 0x7FFFu + ((u >> 16) & 1u);   // RNE
    return (short)(u >> 16);
}

// --- init: agg = entity_emb, kg(=d_out) = 0 ---
__global__ void init_kernel(float* __restrict__ agg, float* __restrict__ kg,
                            const float* __restrict__ ent, int n) {
    int i = blockIdx.x * blockDim.x + threadIdx.x;
    if (i < n) { agg[i] = ent[i]; kg[i] = 0.0f; }
}

// ============ one-time CSR build (counting sort by head) ============

__global__ void hist_kernel(int* __restrict__ deg, const int* __restrict__ head, int E) {
    int e = blockIdx.x * blockDim.x + threadIdx.x;
    if (e < E) atomicAdd(&deg[head[e]], 1);
}

// block-level exclusive scan: 1024 elements per block (256 thr x 4)
__global__ void scan_blocks(const int* __restrict__ deg, int* __restrict__ excl,
                            int* __restrict__ bsum, int n) {
    __shared__ int wsum[4];
    int base = blockIdx.x * 1024;
    int t = threadIdx.x;
    int lane = t & 63, wid = t >> 6;
    int idx = base + t * 4;
    int v0 = (idx + 0 < n) ? deg[idx + 0] : 0;
    int v1 = (idx + 1 < n) ? deg[idx + 1] : 0;
    int v2 = (idx + 2 < n) ? deg[idx + 2] : 0;
    int v3 = (idx + 3 < n) ? deg[idx + 3] : 0;
    int s0 = v0, s1 = s0 + v1, s2 = s1 + v2, s3 = s2 + v3;
    int tsum = s3;
    int inc = tsum;
#pragma unroll
    for (int o = 1; o < 64; o <<= 1) { int u = __shfl_up(inc, o, 64); if (lane >= o) inc += u; }
    if (lane == 63) wsum[wid] = inc;
    __syncthreads();
    int woff = 0;
#pragma unroll
    for (int w = 0; w < 4; ++w) if (w < wid) woff += wsum[w];
    int texcl = woff + inc - tsum;
    if (idx + 0 < n) excl[idx + 0] = texcl;
    if (idx + 1 < n) excl[idx + 1] = texcl + s0;
    if (idx + 2 < n) excl[idx + 2] = texcl + s1;
    if (idx + 3 < n) excl[idx + 3] = texcl + s2;
    if (t == 255) bsum[blockIdx.x] = woff + inc;
}

__global__ void scan_sums(int* __restrict__ bsum, int* __restrict__ excl, int nb, int n, int E) {
    int acc = 0;
    for (int b = 0; b < nb; ++b) { int v = bsum[b]; bsum[b] = acc; acc += v; }
    excl[n] = E;
}

__global__ void scan_add(int* __restrict__ excl, const int* __restrict__ bsum, int n) {
    int i = blockIdx.x * blockDim.x + threadIdx.x;
    if (i < n) excl[i] += bsum[i >> 10];
}

__global__ void sort_scatter(const int* __restrict__ head, const int* __restrict__ tail,
                             const int* __restrict__ etype, const int* __restrict__ offsets,
                             int* __restrict__ cursor, int* __restrict__ shead,
                             int* __restrict__ stail, int* __restrict__ setype, int E) {
    int e = blockIdx.x * blockDim.x + threadIdx.x;
    if (e >= E) return;
    int h = head[e];
    int pos = offsets[h] + atomicAdd(&cursor[h], 1);
    shead[pos] = h;
    stail[pos] = tail[e];
    setype[pos] = etype[e];
}

// ============ per-hop kernels ============

// Build B fragments (2 k-halves x 4 n-tiles) from a 64x64 fp32 row-major matrix.
__device__ __forceinline__ void build_bfrags(bf16x8 bfrag[2][4], const float* __restrict__ W,
                                             int lane) {
    int koff = (lane >> 4) * 8;
    int n = lane & 15;
#pragma unroll
    for (int kh = 0; kh < 2; ++kh)
#pragma unroll
        for (int nt = 0; nt < 4; ++nt) {
            bf16x8 b;
#pragma unroll
            for (int j = 0; j < 8; ++j)
                b[j] = f2bf(W[(kh * 32 + koff + j) * EMB + nt * 16 + n]);
            bfrag[kh][nt] = b;
        }
}

// --- Q = agg @ q_w via MFMA: 16 rows per wave-tile ---
__global__ void qproj_mfma_kernel(float* __restrict__ Qout, const float* __restrict__ agg,
                                  const float* __restrict__ qw, int N) {
    int lane = threadIdx.x & 63;
    int gwave = blockIdx.x * (blockDim.x >> 6) + (threadIdx.x >> 6);
    int nwaves = gridDim.x * (blockDim.x >> 6);
    int row = lane & 15;
    int g = lane >> 4;
    int koff = g * 8;

    bf16x8 bfrag[2][4];
    build_bfrags(bfrag, qw, lane);

    int ntiles = (N + 15) >> 4;
    for (int tile = gwave; tile < ntiles; tile += nwaves) {
        int rIdx = min(tile * 16 + row, N - 1);
        const float* ag = agg + (size_t)rIdx * EMB;
        bf16x8 a0, a1;
#pragma unroll
        for (int j = 0; j < 8; ++j) a0[j] = f2bf(ag[koff + j]);
#pragma unroll
        for (int j = 0; j < 8; ++j) a1[j] = f2bf(ag[32 + koff + j]);
#pragma unroll
        for (int nt = 0; nt < 4; ++nt) {
            f32x4 acc = {0.f, 0.f, 0.f, 0.f};
            acc = __builtin_amdgcn_mfma_f32_16x16x32_bf16(a0, bfrag[0][nt], acc, 0, 0, 0);
            acc = __builtin_amdgcn_mfma_f32_16x16x32_bf16(a1, bfrag[1][nt], acc, 0, 0, 0);
#pragma unroll
            for (int reg = 0; reg < 4; ++reg) {
                int n2 = tile * 16 + g * 4 + reg;
                if (n2 < N) Qout[(size_t)n2 * EMB + nt * 16 + (lane & 15)] = acc[reg];
            }
        }
    }
}

// --- per-edge attention via MFMA over SORTED edges ---
__global__ void att_mfma_kernel(float* __restrict__ att,
                                const float* __restrict__ agg, const float* __restrict__ Q,
                                const float* __restrict__ eemb, const float* __restrict__ kw,
                                const int* __restrict__ shead, const int* __restrict__ stail,
                                const int* __restrict__ setype, int E) {
    int lane = threadIdx.x & 63;
    int gwave = blockIdx.x * (blockDim.x >> 6) + (threadIdx.x >> 6);
    int nwaves = gridDim.x * (blockDim.x >> 6);
    int row = lane & 15;
    int g = lane >> 4;
    int koff = g * 8;

    bf16x8 bfrag[2][4];
    build_bfrags(bfrag, kw, lane);

    int ntiles = (E + 15) >> 4;
    for (int tile = gwave; tile < ntiles; tile += nwaves) {
        int eld = min(tile * 16 + row, E - 1);
        int t = stail[eld], h = shead[eld], r = setype[eld];
        const float* ag = agg + (size_t)t * EMB;
        const float* rl = eemb + r * EMB;
        bf16x8 a0, a1;
#pragma unroll
        for (int j = 0; j < 8; ++j) a0[j] = f2bf(rl[koff + j] * ag[koff + j]);
#pragma unroll
        for (int j = 0; j < 8; ++j) a1[j] = f2bf(rl[32 + koff + j] * ag[32 + koff + j]);

        float sums0 = 0.f, sums1 = 0.f, sums2 = 0.f, sums3 = 0.f;
#pragma unroll
        for (int nt = 0; nt < 4; ++nt) {
            f32x4 acc = {0.f, 0.f, 0.f, 0.f};
            acc = __builtin_amdgcn_mfma_f32_16x16x32_bf16(a0, bfrag[0][nt], acc, 0, 0, 0);
            acc = __builtin_amdgcn_mfma_f32_16x16x32_bf16(a1, bfrag[1][nt], acc, 0, 0, 0);
#pragma unroll
            for (int reg = 0; reg < 4; ++reg) {
                int row2 = g * 4 + reg;
                int h2 = __shfl(h, row2, 64);
                float q = Q[(size_t)h2 * EMB + nt * 16 + (lane & 15)];
                float v = q * tanhf(acc[reg]);
                if (reg == 0) sums0 += v;
                else if (reg == 1) sums1 += v;
                else if (reg == 2) sums2 += v;
                else sums3 += v;
            }
        }
#pragma unroll
        for (int m = 1; m <= 8; m <<= 1) {
            sums0 += __shfl_xor(sums0, m, 64);
            sums1 += __shfl_xor(sums1, m, 64);
            sums2 += __shfl_xor(sums2, m, 64);
            sums3 += __shfl_xor(sums3, m, 64);
        }
#pragma unroll
        for (int reg = 0; reg < 4; ++reg) {
            int row2 = g * 4 + reg;
            int e2 = tile * 16 + row2;
            float v = (reg == 0) ? sums0 : (reg == 1) ? sums1 : (reg == 2) ? sums2 : sums3;
            if ((lane & 15) == reg && e2 < E) att[e2] = v;
        }
    }
}

// --- fused per-head softmax + weighted aggregate + mean + l2norm + residual ---
// one wave per head; lane-parallel softmax passes; LDS-broadcast aggregate loop
__global__ void head_agg_kernel(float* __restrict__ aggNew, float* __restrict__ kg,
                                const float* __restrict__ att, const float* __restrict__ aggOld,
                                const float* __restrict__ eemb, const float* __restrict__ ent,
                                const int* __restrict__ offsets, const int* __restrict__ stail,
                                const int* __restrict__ setype, int N, int R) {
    __shared__ float elds[MAXREL * EMB];   // relation embeddings (8 KB for R=32)
    __shared__ int2 pairs[4 * 64];         // per-wave (w, tail|type) chunk

    int tid = threadIdx.x;
    int lane = tid & 63;
    int wid = tid >> 6;
    int RS = (R < MAXREL) ? R : MAXREL;
    for (int i = tid; i < RS * EMB; i += blockDim.x) elds[i] = eemb[i];
    __syncthreads();

    int h = blockIdx.x * (blockDim.x >> 6) + wid;
    if (h >= N) return;
    int beg = offsets[h], end = offsets[h + 1];
    int deg = end - beg;

    // pass 1: max over segment (lane-parallel)
    float m = -3.4e38f;
    for (int c = beg; c < end; c += 64) {
        int e = c + lane;
        if (e < end) m = fmaxf(m, att[e]);
    }
#pragma unroll
    for (int o = 32; o > 0; o >>= 1) m = fmaxf(m, __shfl_xor(m, o, 64));

    // pass 2: sum of exp (lane-parallel)
    float ssum = 0.f;
    for (int c = beg; c < end; c += 64) {
        int e = c + lane;
        if (e < end) ssum += expf(att[e] - m);
    }
#pragma unroll
    for (int o = 32; o > 0; o >>= 1) ssum += __shfl_xor(ssum, o, 64);
    float inv = 1.0f / ssum;

    // pass 3: weighted aggregate; chunk weights into LDS, broadcast-read
    float acc = 0.f;
    int2* mypairs = &pairs[wid * 64];
    for (int c = beg; c < end; c += 64) {
        int e = c + lane;
        int nc = min(64, end - c);
        float w = 0.f; int tr = 0;
        if (e < end) {
            w = expf(att[e] - m) * inv;
            tr = stail[e] | (setype[e] << 20);
        }
        mypairs[lane] = make_int2(__float_as_int(w), tr);
        for (int j = 0; j < nc; ++j) {
            int2 p = mypairs[j];                        // ds_read_b64 broadcast
            float wj = __int_as_float(p.x);
            int tj = p.y & 0xFFFFF;
            int rj = p.y >> 20;
            float ew = (rj < RS) ? elds[rj * EMB + lane]
                                 : eemb[(size_t)rj * EMB + lane];
            acc += wj * ew * aggOld[(size_t)tj * EMB + lane];
        }
    }

    float c = (float)max(deg, 1);
    float v = acc / c;
    float ss = v * v;
#pragma unroll
    for (int o = 32; o > 0; o >>= 1) ss += __shfl_xor(ss, o, 64);
    float nrm = sqrtf(ss);
    v = v / fmaxf(nrm, 1e-12f);
    aggNew[(size_t)h * EMB + lane] = v;
    kg[(size_t)h * EMB + lane] += v + ent[(size_t)h * EMB + lane];
}

extern "C" void kernel_launch(void* const* d_in, const int* in_sizes, int n_in,
                              void* d_out, int out_size, void* d_ws, size_t ws_size,
                              hipStream_t stream) {
    const float* ent  = (const float*)d_in[0];
    const float* eemb = (const float*)d_in[1];
    const float* qw   = (const float*)d_in[2];
    const float* kw   = (const float*)d_in[3];
    const int* eidx  = (const int*)d_in[4];
    const int* etype = (const int*)d_in[5];

    const int N = in_sizes[0] / EMB;
    const int R = in_sizes[1] / EMB;
    const int E = in_sizes[5];
    const int* head = eidx;
    const int* tail = eidx + E;

    float* kg = (float*)d_out;

    // workspace layout
    float* agg_a = (float*)d_ws;                 // N*EMB
    float* agg_b = agg_a + (size_t)N * EMB;      // N*EMB
    float* Qb    = agg_b + (size_t)N * EMB;      // N*EMB
    float* att   = Qb    + (size_t)N * EMB;      // E
    int* offsets = (int*)(att + E);              // N+1
    int* deg     = offsets + (N + 1);            // N
    int* cursor  = deg + N;                      // N
    int* bsum    = cursor + N;                   // up to 1024
    int* shead   = bsum + 1024;                  // E
    int* stail   = shead + E;                    // E
    int* setype  = stail + E;                    // E

    const int NT = 256;
    const int WPB = NT / 64;
    const int nb = (N + 1023) / 1024;

    // one-time: init + CSR build
    init_kernel<<<(N * EMB + NT - 1) / NT, NT, 0, stream>>>(agg_a, kg, ent, N * EMB);
    hipMemsetAsync(deg, 0, (size_t)N * 4, stream);
    hipMemsetAsync(cursor, 0, (size_t)N * 4, stream);
    hist_kernel<<<(E + NT - 1) / NT, NT, 0, stream>>>(deg, head, E);
    scan_blocks<<<nb, NT, 0, stream>>>(deg, offsets, bsum, N);
    scan_sums<<<1, 1, 0, stream>>>(bsum, offsets, nb, N, E);
    scan_add<<<(N + NT - 1) / NT, NT, 0, stream>>>(offsets, bsum, N);
    sort_scatter<<<(E + NT - 1) / NT, NT, 0, stream>>>(head, tail, etype, offsets, cursor,
                                                       shead, stail, setype, E);

    float* cur = agg_a;
    float* nxt = agg_b;
    for (int hop = 0; hop < 2; ++hop) {
        qproj_mfma_kernel<<<512, NT, 0, stream>>>(Qb, cur, qw, N);
        att_mfma_kernel<<<1024, NT, 0, stream>>>(att, cur, Qb, eemb, kw,
                                                 shead, stail, setype, E);
        head_agg_kernel<<<(N + WPB - 1) / WPB, NT, 0, stream>>>(nxt, kg, att, cur, eemb, ent,
                                                                offsets, stail, setype, N, R);
        float* tmp = cur; cur = nxt; nxt = tmp;
    }
}

// Round 6
// 575.797 us; speedup vs baseline: 5.7723x; 1.0476x over previous
//
#include <hip/hip_runtime.h>
#include <math.h>

#define EMB 64
#define MAXREL 32

typedef short bf16x8 __attribute__((ext_vector_type(8)));
typedef float f32x4 __attribute__((ext_vector_type(4)));

__device__ __forceinline__ short f2bf(float f) {
    unsigned u = __float_as_uint(f);
    u += 0x7FFFu + ((u >> 16) & 1u);   // RNE
    return (short)(u >> 16);
}

// --- init: agg = entity_emb, kg(=d_out) = 0 (float4) ---
__global__ void init_kernel(float4* __restrict__ agg, float4* __restrict__ kg,
                            const float4* __restrict__ ent, int n4) {
    int i = blockIdx.x * blockDim.x + threadIdx.x;
    if (i < n4) { agg[i] = ent[i]; kg[i] = make_float4(0.f, 0.f, 0.f, 0.f); }
}

// ============ one-time CSR build (counting sort by head) ============

__global__ void hist_kernel(int* __restrict__ deg, const int* __restrict__ head, int E) {
    int e = blockIdx.x * blockDim.x + threadIdx.x;
    if (e < E) atomicAdd(&deg[head[e]], 1);
}

// block-level exclusive scan: 1024 elements per block (256 thr x 4)
__global__ void scan_blocks(const int* __restrict__ deg, int* __restrict__ excl,
                            int* __restrict__ bsum, int n) {
    __shared__ int wsum[4];
    int base = blockIdx.x * 1024;
    int t = threadIdx.x;
    int lane = t & 63, wid = t >> 6;
    int idx = base + t * 4;
    int v0 = (idx + 0 < n) ? deg[idx + 0] : 0;
    int v1 = (idx + 1 < n) ? deg[idx + 1] : 0;
    int v2 = (idx + 2 < n) ? deg[idx + 2] : 0;
    int v3 = (idx + 3 < n) ? deg[idx + 3] : 0;
    int s0 = v0, s1 = s0 + v1, s2 = s1 + v2, s3 = s2 + v3;
    int tsum = s3;
    int inc = tsum;
#pragma unroll
    for (int o = 1; o < 64; o <<= 1) { int u = __shfl_up(inc, o, 64); if (lane >= o) inc += u; }
    if (lane == 63) wsum[wid] = inc;
    __syncthreads();
    int woff = 0;
#pragma unroll
    for (int w = 0; w < 4; ++w) if (w < wid) woff += wsum[w];
    int texcl = woff + inc - tsum;
    if (idx + 0 < n) excl[idx + 0] = texcl;
    if (idx + 1 < n) excl[idx + 1] = texcl + s0;
    if (idx + 2 < n) excl[idx + 2] = texcl + s1;
    if (idx + 3 < n) excl[idx + 3] = texcl + s2;
    if (t == 255) bsum[blockIdx.x] = woff + inc;
}

__global__ void scan_sums(int* __restrict__ bsum, int* __restrict__ excl, int nb, int n, int E) {
    int acc = 0;
    for (int b = 0; b < nb; ++b) { int v = bsum[b]; bsum[b] = acc; acc += v; }
    excl[n] = E;
}

__global__ void scan_add(int* __restrict__ excl, const int* __restrict__ bsum, int n) {
    int i = blockIdx.x * blockDim.x + threadIdx.x;
    if (i < n) excl[i] += bsum[i >> 10];
}

__global__ void sort_scatter(const int* __restrict__ head, const int* __restrict__ tail,
                             const int* __restrict__ etype, const int* __restrict__ offsets,
                             int* __restrict__ cursor, int* __restrict__ shead,
                             int* __restrict__ stail, int* __restrict__ setype, int E) {
    int e = blockIdx.x * blockDim.x + threadIdx.x;
    if (e >= E) return;
    int h = head[e];
    int pos = offsets[h] + atomicAdd(&cursor[h], 1);
    shead[pos] = h;
    stail[pos] = tail[e];
    setype[pos] = etype[e];
}

// ============ per-hop kernels ============

// Build B fragments (2 k-halves x 4 n-tiles) from a 64x64 fp32 row-major matrix.
__device__ __forceinline__ void build_bfrags(bf16x8 bfrag[2][4], const float* __restrict__ W,
                                             int lane) {
    int koff = (lane >> 4) * 8;
    int n = lane & 15;
#pragma unroll
    for (int kh = 0; kh < 2; ++kh)
#pragma unroll
        for (int nt = 0; nt < 4; ++nt) {
            bf16x8 b;
#pragma unroll
            for (int j = 0; j < 8; ++j)
                b[j] = f2bf(W[(kh * 32 + koff + j) * EMB + nt * 16 + n]);
            bfrag[kh][nt] = b;
        }
}

__device__ __forceinline__ void pack_a(bf16x8& a, float4 p0, float4 p1, float4 q0, float4 q1) {
    a[0] = f2bf(p0.x * q0.x); a[1] = f2bf(p0.y * q0.y);
    a[2] = f2bf(p0.z * q0.z); a[3] = f2bf(p0.w * q0.w);
    a[4] = f2bf(p1.x * q1.x); a[5] = f2bf(p1.y * q1.y);
    a[6] = f2bf(p1.z * q1.z); a[7] = f2bf(p1.w * q1.w);
}

// --- Q = agg @ q_w via MFMA: 16 rows per wave-tile ---
__global__ void qproj_mfma_kernel(float* __restrict__ Qout, const float* __restrict__ agg,
                                  const float* __restrict__ qw, int N) {
    int lane = threadIdx.x & 63;
    int gwave = blockIdx.x * (blockDim.x >> 6) + (threadIdx.x >> 6);
    int nwaves = gridDim.x * (blockDim.x >> 6);
    int row = lane & 15;
    int g = lane >> 4;

    bf16x8 bfrag[2][4];
    build_bfrags(bfrag, qw, lane);

    int ntiles = (N + 15) >> 4;
    for (int tile = gwave; tile < ntiles; tile += nwaves) {
        int rIdx = min(tile * 16 + row, N - 1);
        const float4* ag4 = (const float4*)(agg + (size_t)rIdx * EMB);
        float4 x0 = ag4[g * 2], x1 = ag4[g * 2 + 1];
        float4 x2 = ag4[8 + g * 2], x3 = ag4[8 + g * 2 + 1];
        bf16x8 a0, a1;
        a0[0]=f2bf(x0.x); a0[1]=f2bf(x0.y); a0[2]=f2bf(x0.z); a0[3]=f2bf(x0.w);
        a0[4]=f2bf(x1.x); a0[5]=f2bf(x1.y); a0[6]=f2bf(x1.z); a0[7]=f2bf(x1.w);
        a1[0]=f2bf(x2.x); a1[1]=f2bf(x2.y); a1[2]=f2bf(x2.z); a1[3]=f2bf(x2.w);
        a1[4]=f2bf(x3.x); a1[5]=f2bf(x3.y); a1[6]=f2bf(x3.z); a1[7]=f2bf(x3.w);
#pragma unroll
        for (int nt = 0; nt < 4; ++nt) {
            f32x4 acc = {0.f, 0.f, 0.f, 0.f};
            acc = __builtin_amdgcn_mfma_f32_16x16x32_bf16(a0, bfrag[0][nt], acc, 0, 0, 0);
            acc = __builtin_amdgcn_mfma_f32_16x16x32_bf16(a1, bfrag[1][nt], acc, 0, 0, 0);
#pragma unroll
            for (int reg = 0; reg < 4; ++reg) {
                int n2 = tile * 16 + g * 4 + reg;
                if (n2 < N) Qout[(size_t)n2 * EMB + nt * 16 + (lane & 15)] = acc[reg];
            }
        }
    }
}

// --- per-edge attention via MFMA over SORTED edges ---
__global__ void att_mfma_kernel(float* __restrict__ att,
                                const float* __restrict__ agg, const float* __restrict__ Q,
                                const float* __restrict__ eemb, const float* __restrict__ kw,
                                const int* __restrict__ shead, const int* __restrict__ stail,
                                const int* __restrict__ setype, int E) {
    int lane = threadIdx.x & 63;
    int gwave = blockIdx.x * (blockDim.x >> 6) + (threadIdx.x >> 6);
    int nwaves = gridDim.x * (blockDim.x >> 6);
    int row = lane & 15;
    int g = lane >> 4;

    bf16x8 bfrag[2][4];
    build_bfrags(bfrag, kw, lane);

    int ntiles = (E + 15) >> 4;
    for (int tile = gwave; tile < ntiles; tile += nwaves) {
        int eld = min(tile * 16 + row, E - 1);
        int t = stail[eld], h = shead[eld], r = setype[eld];
        const float4* ag4 = (const float4*)(agg + (size_t)t * EMB);
        const float4* rl4 = (const float4*)(eemb + (size_t)r * EMB);
        float4 x0 = ag4[g * 2], x1 = ag4[g * 2 + 1];
        float4 x2 = ag4[8 + g * 2], x3 = ag4[8 + g * 2 + 1];
        float4 y0 = rl4[g * 2], y1 = rl4[g * 2 + 1];
        float4 y2 = rl4[8 + g * 2], y3 = rl4[8 + g * 2 + 1];
        bf16x8 a0, a1;
        pack_a(a0, x0, x1, y0, y1);
        pack_a(a1, x2, x3, y2, y3);

        float sums0 = 0.f, sums1 = 0.f, sums2 = 0.f, sums3 = 0.f;
#pragma unroll
        for (int nt = 0; nt < 4; ++nt) {
            f32x4 acc = {0.f, 0.f, 0.f, 0.f};
            acc = __builtin_amdgcn_mfma_f32_16x16x32_bf16(a0, bfrag[0][nt], acc, 0, 0, 0);
            acc = __builtin_amdgcn_mfma_f32_16x16x32_bf16(a1, bfrag[1][nt], acc, 0, 0, 0);
#pragma unroll
            for (int reg = 0; reg < 4; ++reg) {
                int row2 = g * 4 + reg;
                int h2 = __shfl(h, row2, 64);
                float q = Q[(size_t)h2 * EMB + nt * 16 + (lane & 15)];
                float v = q * tanhf(acc[reg]);
                if (reg == 0) sums0 += v;
                else if (reg == 1) sums1 += v;
                else if (reg == 2) sums2 += v;
                else sums3 += v;
            }
        }
#pragma unroll
        for (int m = 1; m <= 8; m <<= 1) {
            sums0 += __shfl_xor(sums0, m, 64);
            sums1 += __shfl_xor(sums1, m, 64);
            sums2 += __shfl_xor(sums2, m, 64);
            sums3 += __shfl_xor(sums3, m, 64);
        }
#pragma unroll
        for (int reg = 0; reg < 4; ++reg) {
            int row2 = g * 4 + reg;
            int e2 = tile * 16 + row2;
            float v = (reg == 0) ? sums0 : (reg == 1) ? sums1 : (reg == 2) ? sums2 : sums3;
            if ((lane & 15) == reg && e2 < E) att[e2] = v;
        }
    }
}

// --- fused per-head softmax + weighted aggregate + mean + l2norm + residual ---
// one wave per head; lane-parallel softmax; quad-packed float4 aggregate loop
__global__ void head_agg_kernel(float* __restrict__ aggNew, float* __restrict__ kg,
                                const float* __restrict__ att, const float* __restrict__ aggOld,
                                const float* __restrict__ eemb, const float* __restrict__ ent,
                                const int* __restrict__ offsets, const int* __restrict__ stail,
                                const int* __restrict__ setype, int N, int R) {
    __shared__ float4 elds4[MAXREL * 16];  // relation embeddings (8 KB for R=32)
    __shared__ int2 pairs[4 * 64];         // per-wave (w, tail|type) chunk

    int tid = threadIdx.x;
    int lane = tid & 63;
    int wid = tid >> 6;
    int RS = (R < MAXREL) ? R : MAXREL;
    for (int i = tid; i < RS * 16; i += blockDim.x) elds4[i] = ((const float4*)eemb)[i];
    __syncthreads();

    int h = blockIdx.x * (blockDim.x >> 6) + wid;
    if (h >= N) return;
    int beg = offsets[h], end = offsets[h + 1];
    int deg = end - beg;

    // pass 1: max over segment (lane-parallel)
    float m = -3.4e38f;
    for (int c = beg; c < end; c += 64) {
        int e = c + lane;
        if (e < end) m = fmaxf(m, att[e]);
    }
#pragma unroll
    for (int o = 32; o > 0; o >>= 1) m = fmaxf(m, __shfl_xor(m, o, 64));

    // pass 2: sum of exp (lane-parallel)
    float ssum = 0.f;
    for (int c = beg; c < end; c += 64) {
        int e = c + lane;
        if (e < end) ssum += expf(att[e] - m);
    }
#pragma unroll
    for (int o = 32; o > 0; o >>= 1) ssum += __shfl_xor(ssum, o, 64);
    float inv = 1.0f / ssum;

    // pass 3: quad-packed weighted aggregate: 4 edges / iteration, float4 / lane
    int sub = lane >> 4;       // which edge of the quad
    int q = lane & 15;         // dim quad (4 floats)
    float4 acc4 = make_float4(0.f, 0.f, 0.f, 0.f);
    int2* mypairs = &pairs[wid * 64];
    for (int c = beg; c < end; c += 64) {
        int e = c + lane;
        int nc = min(64, end - c);
        float w = 0.f; int tr = 0;
        if (e < end) {
            w = expf(att[e] - m) * inv;
            tr = stail[e] | (setype[e] << 20);
        }
        mypairs[lane] = make_int2(__float_as_int(w), tr);
        for (int j = 0; j < nc; j += 4) {
            int jj = j + sub;
            int2 p = mypairs[min(jj, nc - 1)];
            float wj = (jj < nc) ? __int_as_float(p.x) : 0.f;
            int tj = p.y & 0xFFFFF;
            int rj = p.y >> 20;
            float4 ew = (rj < RS) ? elds4[rj * 16 + q]
                                  : ((const float4*)eemb)[(size_t)rj * 16 + q];
            float4 x = ((const float4*)aggOld)[(size_t)tj * 16 + q];
            acc4.x += wj * ew.x * x.x;
            acc4.y += wj * ew.y * x.y;
            acc4.z += wj * ew.z * x.z;
            acc4.w += wj * ew.w * x.w;
        }
    }
    // combine the 4 sub-group partials (lanes l, l^16, l^32, l^48 share q)
#pragma unroll
    for (int o = 16; o <= 32; o <<= 1) {
        acc4.x += __shfl_xor(acc4.x, o, 64);
        acc4.y += __shfl_xor(acc4.y, o, 64);
        acc4.z += __shfl_xor(acc4.z, o, 64);
        acc4.w += __shfl_xor(acc4.w, o, 64);
    }

    float cdeg = (float)max(deg, 1);
    float4 v = make_float4(acc4.x / cdeg, acc4.y / cdeg, acc4.z / cdeg, acc4.w / cdeg);
    float ss = v.x * v.x + v.y * v.y + v.z * v.z + v.w * v.w;
#pragma unroll
    for (int o = 1; o <= 8; o <<= 1) ss += __shfl_xor(ss, o, 64);
    float rinv = 1.0f / fmaxf(sqrtf(ss), 1e-12f);
    v.x *= rinv; v.y *= rinv; v.z *= rinv; v.w *= rinv;

    if (sub == 0) {
        ((float4*)aggNew)[(size_t)h * 16 + q] = v;
        float4 kgv = ((float4*)kg)[(size_t)h * 16 + q];
        float4 ev = ((const float4*)ent)[(size_t)h * 16 + q];
        kgv.x += v.x + ev.x; kgv.y += v.y + ev.y;
        kgv.z += v.z + ev.z; kgv.w += v.w + ev.w;
        ((float4*)kg)[(size_t)h * 16 + q] = kgv;
    }
}

extern "C" void kernel_launch(void* const* d_in, const int* in_sizes, int n_in,
                              void* d_out, int out_size, void* d_ws, size_t ws_size,
                              hipStream_t stream) {
    const float* ent  = (const float*)d_in[0];
    const float* eemb = (const float*)d_in[1];
    const float* qw   = (const float*)d_in[2];
    const float* kw   = (const float*)d_in[3];
    const int* eidx  = (const int*)d_in[4];
    const int* etype = (const int*)d_in[5];

    const int N = in_sizes[0] / EMB;
    const int R = in_sizes[1] / EMB;
    const int E = in_sizes[5];
    const int* head = eidx;
    const int* tail = eidx + E;

    float* kg = (float*)d_out;

    // workspace layout
    float* agg_a = (float*)d_ws;                 // N*EMB
    float* agg_b = agg_a + (size_t)N * EMB;      // N*EMB
    float* Qb    = agg_b + (size_t)N * EMB;      // N*EMB
    float* att   = Qb    + (size_t)N * EMB;      // E
    int* offsets = (int*)(att + E);              // N+1
    int* deg     = offsets + (N + 1);            // N
    int* cursor  = deg + N;                      // N
    int* bsum    = cursor + N;                   // up to 1024
    int* shead   = bsum + 1024;                  // E
    int* stail   = shead + E;                    // E
    int* setype  = stail + E;                    // E

    const int NT = 256;
    const int WPB = NT / 64;
    const int nb = (N + 1023) / 1024;

    // one-time: init + CSR build
    init_kernel<<<(N * EMB / 4 + NT - 1) / NT, NT, 0, stream>>>((float4*)agg_a, (float4*)kg,
                                                                (const float4*)ent, N * EMB / 4);
    hipMemsetAsync(deg, 0, (size_t)N * 4, stream);
    hipMemsetAsync(cursor, 0, (size_t)N * 4, stream);
    hist_kernel<<<(E + NT - 1) / NT, NT, 0, stream>>>(deg, head, E);
    scan_blocks<<<nb, NT, 0, stream>>>(deg, offsets, bsum, N);
    scan_sums<<<1, 1, 0, stream>>>(bsum, offsets, nb, N, E);
    scan_add<<<(N + NT - 1) / NT, NT, 0, stream>>>(offsets, bsum, N);
    sort_scatter<<<(E + NT - 1) / NT, NT, 0, stream>>>(head, tail, etype, offsets, cursor,
                                                       shead, stail, setype, E);

    float* cur = agg_a;
    float* nxt = agg_b;
    for (int hop = 0; hop < 2; ++hop) {
        qproj_mfma_kernel<<<512, NT, 0, stream>>>(Qb, cur, qw, N);
        att_mfma_kernel<<<1024, NT, 0, stream>>>(att, cur, Qb, eemb, kw,
                                                 shead, stail, setype, E);
        head_agg_kernel<<<(N + WPB - 1) / WPB, NT, 0, stream>>>(nxt, kg, att, cur, eemb, ent,
                                                                offsets, stail, setype, N, R);
        float* tmp = cur; cur = nxt; nxt = tmp;
    }
}

// Round 7
// 529.947 us; speedup vs baseline: 6.2717x; 1.0865x over previous
//
#include <hip/hip_runtime.h>
#include <math.h>

#define EMB 64
#define MAXREL 32

typedef short bf16x8 __attribute__((ext_vector_type(8)));
typedef float f32x4 __attribute__((ext_vector_type(4)));

__device__ __forceinline__ short f2bf(float f) {
    unsigned u = __float_as_uint(f);
    u += 0x7FFFu + ((u >> 16) & 1u);   // RNE
    return (short)(u >> 16);
}

// fast tanh: 1 - 2/(e^{2|x|}+1), sign restored; exact ±1 saturation for big |x|
__device__ __forceinline__ float fast_tanh(float x) {
    float ax = fabsf(x);
    float z = __expf(2.0f * ax);
    float r = 1.0f - 2.0f / (z + 1.0f);
    return copysignf(r, x);
}

// --- init: agg = entity_emb, kg(=d_out) = 0 (float4) ---
__global__ void init_kernel(float4* __restrict__ agg, float4* __restrict__ kg,
                            const float4* __restrict__ ent, int n4) {
    int i = blockIdx.x * blockDim.x + threadIdx.x;
    if (i < n4) { agg[i] = ent[i]; kg[i] = make_float4(0.f, 0.f, 0.f, 0.f); }
}

// ============ one-time CSR build (counting sort by head) ============

__global__ void hist_kernel(int* __restrict__ deg, const int* __restrict__ head, int E) {
    int e = blockIdx.x * blockDim.x + threadIdx.x;
    if (e < E) atomicAdd(&deg[head[e]], 1);
}

// block-level exclusive scan: 1024 elements per block (256 thr x 4)
__global__ void scan_blocks(const int* __restrict__ deg, int* __restrict__ excl,
                            int* __restrict__ bsum, int n) {
    __shared__ int wsum[4];
    int base = blockIdx.x * 1024;
    int t = threadIdx.x;
    int lane = t & 63, wid = t >> 6;
    int idx = base + t * 4;
    int v0 = (idx + 0 < n) ? deg[idx + 0] : 0;
    int v1 = (idx + 1 < n) ? deg[idx + 1] : 0;
    int v2 = (idx + 2 < n) ? deg[idx + 2] : 0;
    int v3 = (idx + 3 < n) ? deg[idx + 3] : 0;
    int s0 = v0, s1 = s0 + v1, s2 = s1 + v2, s3 = s2 + v3;
    int tsum = s3;
    int inc = tsum;
#pragma unroll
    for (int o = 1; o < 64; o <<= 1) { int u = __shfl_up(inc, o, 64); if (lane >= o) inc += u; }
    if (lane == 63) wsum[wid] = inc;
    __syncthreads();
    int woff = 0;
#pragma unroll
    for (int w = 0; w < 4; ++w) if (w < wid) woff += wsum[w];
    int texcl = woff + inc - tsum;
    if (idx + 0 < n) excl[idx + 0] = texcl;
    if (idx + 1 < n) excl[idx + 1] = texcl + s0;
    if (idx + 2 < n) excl[idx + 2] = texcl + s1;
    if (idx + 3 < n) excl[idx + 3] = texcl + s2;
    if (t == 255) bsum[blockIdx.x] = woff + inc;
}

__global__ void scan_sums(int* __restrict__ bsum, int* __restrict__ excl, int nb, int n, int E) {
    int acc = 0;
    for (int b = 0; b < nb; ++b) { int v = bsum[b]; bsum[b] = acc; acc += v; }
    excl[n] = E;
}

__global__ void scan_add(int* __restrict__ excl, const int* __restrict__ bsum, int n) {
    int i = blockIdx.x * blockDim.x + threadIdx.x;
    if (i < n) excl[i] += bsum[i >> 10];
}

// packed sorted-edge record: .x = head, .y = tail | (type<<20)
__global__ void sort_scatter(const int* __restrict__ head, const int* __restrict__ tail,
                             const int* __restrict__ etype, const int* __restrict__ offsets,
                             int* __restrict__ cursor, int2* __restrict__ spair, int E) {
    int e = blockIdx.x * blockDim.x + threadIdx.x;
    if (e >= E) return;
    int h = head[e];
    int pos = offsets[h] + atomicAdd(&cursor[h], 1);
    spair[pos] = make_int2(h, tail[e] | (etype[e] << 20));
}

// ============ per-hop kernels ============

// Build B fragments (2 k-halves x 4 n-tiles) from a 64x64 fp32 row-major matrix.
__device__ __forceinline__ void build_bfrags(bf16x8 bfrag[2][4], const float* __restrict__ W,
                                             int lane) {
    int koff = (lane >> 4) * 8;
    int n = lane & 15;
#pragma unroll
    for (int kh = 0; kh < 2; ++kh)
#pragma unroll
        for (int nt = 0; nt < 4; ++nt) {
            bf16x8 b;
#pragma unroll
            for (int j = 0; j < 8; ++j)
                b[j] = f2bf(W[(kh * 32 + koff + j) * EMB + nt * 16 + n]);
            bfrag[kh][nt] = b;
        }
}

__device__ __forceinline__ void pack_a(bf16x8& a, float4 p0, float4 p1, float4 q0, float4 q1) {
    a[0] = f2bf(p0.x * q0.x); a[1] = f2bf(p0.y * q0.y);
    a[2] = f2bf(p0.z * q0.z); a[3] = f2bf(p0.w * q0.w);
    a[4] = f2bf(p1.x * q1.x); a[5] = f2bf(p1.y * q1.y);
    a[6] = f2bf(p1.z * q1.z); a[7] = f2bf(p1.w * q1.w);
}

// --- Q = agg @ q_w via MFMA: 16 rows per wave-tile ---
__global__ void qproj_mfma_kernel(float* __restrict__ Qout, const float* __restrict__ agg,
                                  const float* __restrict__ qw, int N) {
    int lane = threadIdx.x & 63;
    int gwave = blockIdx.x * (blockDim.x >> 6) + (threadIdx.x >> 6);
    int nwaves = gridDim.x * (blockDim.x >> 6);
    int row = lane & 15;
    int g = lane >> 4;

    bf16x8 bfrag[2][4];
    build_bfrags(bfrag, qw, lane);

    int ntiles = (N + 15) >> 4;
    for (int tile = gwave; tile < ntiles; tile += nwaves) {
        int rIdx = min(tile * 16 + row, N - 1);
        const float4* ag4 = (const float4*)(agg + (size_t)rIdx * EMB);
        float4 x0 = ag4[g * 2], x1 = ag4[g * 2 + 1];
        float4 x2 = ag4[8 + g * 2], x3 = ag4[8 + g * 2 + 1];
        bf16x8 a0, a1;
        a0[0]=f2bf(x0.x); a0[1]=f2bf(x0.y); a0[2]=f2bf(x0.z); a0[3]=f2bf(x0.w);
        a0[4]=f2bf(x1.x); a0[5]=f2bf(x1.y); a0[6]=f2bf(x1.z); a0[7]=f2bf(x1.w);
        a1[0]=f2bf(x2.x); a1[1]=f2bf(x2.y); a1[2]=f2bf(x2.z); a1[3]=f2bf(x2.w);
        a1[4]=f2bf(x3.x); a1[5]=f2bf(x3.y); a1[6]=f2bf(x3.z); a1[7]=f2bf(x3.w);
#pragma unroll
        for (int nt = 0; nt < 4; ++nt) {
            f32x4 acc = {0.f, 0.f, 0.f, 0.f};
            acc = __builtin_amdgcn_mfma_f32_16x16x32_bf16(a0, bfrag[0][nt], acc, 0, 0, 0);
            acc = __builtin_amdgcn_mfma_f32_16x16x32_bf16(a1, bfrag[1][nt], acc, 0, 0, 0);
#pragma unroll
            for (int reg = 0; reg < 4; ++reg) {
                int n2 = tile * 16 + g * 4 + reg;
                if (n2 < N) Qout[(size_t)n2 * EMB + nt * 16 + (lane & 15)] = acc[reg];
            }
        }
    }
}

// --- per-edge attention via MFMA over SORTED packed edges ---
__global__ void att_mfma_kernel(float* __restrict__ att,
                                const float* __restrict__ agg, const float* __restrict__ Q,
                                const float* __restrict__ eemb, const float* __restrict__ kw,
                                const int2* __restrict__ spair, int E) {
    int lane = threadIdx.x & 63;
    int gwave = blockIdx.x * (blockDim.x >> 6) + (threadIdx.x >> 6);
    int nwaves = gridDim.x * (blockDim.x >> 6);
    int row = lane & 15;
    int g = lane >> 4;

    bf16x8 bfrag[2][4];
    build_bfrags(bfrag, kw, lane);

    int ntiles = (E + 15) >> 4;
    for (int tile = gwave; tile < ntiles; tile += nwaves) {
        int eld = min(tile * 16 + row, E - 1);
        int2 pr = spair[eld];
        int h = pr.x;
        int t = pr.y & 0xFFFFF;
        int r = ((unsigned)pr.y) >> 20;
        const float4* ag4 = (const float4*)(agg + (size_t)t * EMB);
        const float4* rl4 = (const float4*)(eemb + (size_t)r * EMB);
        float4 x0 = ag4[g * 2], x1 = ag4[g * 2 + 1];
        float4 x2 = ag4[8 + g * 2], x3 = ag4[8 + g * 2 + 1];
        float4 y0 = rl4[g * 2], y1 = rl4[g * 2 + 1];
        float4 y2 = rl4[8 + g * 2], y3 = rl4[8 + g * 2 + 1];
        bf16x8 a0, a1;
        pack_a(a0, x0, x1, y0, y1);
        pack_a(a1, x2, x3, y2, y3);

        float sums0 = 0.f, sums1 = 0.f, sums2 = 0.f, sums3 = 0.f;
#pragma unroll
        for (int nt = 0; nt < 4; ++nt) {
            f32x4 acc = {0.f, 0.f, 0.f, 0.f};
            acc = __builtin_amdgcn_mfma_f32_16x16x32_bf16(a0, bfrag[0][nt], acc, 0, 0, 0);
            acc = __builtin_amdgcn_mfma_f32_16x16x32_bf16(a1, bfrag[1][nt], acc, 0, 0, 0);
#pragma unroll
            for (int reg = 0; reg < 4; ++reg) {
                int row2 = g * 4 + reg;
                int h2 = __shfl(h, row2, 64);
                float q = Q[(size_t)h2 * EMB + nt * 16 + (lane & 15)];
                float v = q * fast_tanh(acc[reg]);
                if (reg == 0) sums0 += v;
                else if (reg == 1) sums1 += v;
                else if (reg == 2) sums2 += v;
                else sums3 += v;
            }
        }
#pragma unroll
        for (int m = 1; m <= 8; m <<= 1) {
            sums0 += __shfl_xor(sums0, m, 64);
            sums1 += __shfl_xor(sums1, m, 64);
            sums2 += __shfl_xor(sums2, m, 64);
            sums3 += __shfl_xor(sums3, m, 64);
        }
#pragma unroll
        for (int reg = 0; reg < 4; ++reg) {
            int row2 = g * 4 + reg;
            int e2 = tile * 16 + row2;
            float v = (reg == 0) ? sums0 : (reg == 1) ? sums1 : (reg == 2) ? sums2 : sums3;
            if ((lane & 15) == reg && e2 < E) att[e2] = v;
        }
    }
}

// --- fused per-head softmax + weighted aggregate + mean + l2norm + residual ---
__global__ void head_agg_kernel(float* __restrict__ aggNew, float* __restrict__ kg,
                                const float* __restrict__ att, const float* __restrict__ aggOld,
                                const float* __restrict__ eemb, const float* __restrict__ ent,
                                const int* __restrict__ offsets, const int2* __restrict__ spair,
                                int N, int R) {
    __shared__ float4 elds4[MAXREL * 16];  // relation embeddings (8 KB for R=32)
    __shared__ int2 pairs[4 * 64];         // per-wave (w, tail|type) chunk

    int tid = threadIdx.x;
    int lane = tid & 63;
    int wid = tid >> 6;
    int RS = (R < MAXREL) ? R : MAXREL;
    for (int i = tid; i < RS * 16; i += blockDim.x) elds4[i] = ((const float4*)eemb)[i];
    __syncthreads();

    int h = blockIdx.x * (blockDim.x >> 6) + wid;
    if (h >= N) return;
    int beg = offsets[h], end = offsets[h + 1];
    int deg = end - beg;

    // pass 1: max over segment (lane-parallel)
    float m = -3.4e38f;
    for (int c = beg; c < end; c += 64) {
        int e = c + lane;
        if (e < end) m = fmaxf(m, att[e]);
    }
#pragma unroll
    for (int o = 32; o > 0; o >>= 1) m = fmaxf(m, __shfl_xor(m, o, 64));

    // pass 2: sum of exp (lane-parallel)
    float ssum = 0.f;
    for (int c = beg; c < end; c += 64) {
        int e = c + lane;
        if (e < end) ssum += __expf(att[e] - m);
    }
#pragma unroll
    for (int o = 32; o > 0; o >>= 1) ssum += __shfl_xor(ssum, o, 64);
    float inv = 1.0f / ssum;

    // pass 3: quad-packed weighted aggregate: 4 edges / iteration, float4 / lane
    int sub = lane >> 4;       // which edge of the quad
    int q = lane & 15;         // dim quad (4 floats)
    float4 acc4 = make_float4(0.f, 0.f, 0.f, 0.f);
    int2* mypairs = &pairs[wid * 64];
    for (int c = beg; c < end; c += 64) {
        int e = c + lane;
        int nc = min(64, end - c);
        float w = 0.f; int tr = 0;
        if (e < end) {
            w = __expf(att[e] - m) * inv;
            tr = spair[e].y;
        }
        mypairs[lane] = make_int2(__float_as_int(w), tr);
        for (int j = 0; j < nc; j += 4) {
            int jj = j + sub;
            int2 p = mypairs[min(jj, nc - 1)];
            float wj = (jj < nc) ? __int_as_float(p.x) : 0.f;
            int tj = p.y & 0xFFFFF;
            int rj = ((unsigned)p.y) >> 20;
            float4 ew = (rj < (unsigned)RS) ? elds4[rj * 16 + q]
                                            : ((const float4*)eemb)[(size_t)rj * 16 + q];
            float4 x = ((const float4*)aggOld)[(size_t)tj * 16 + q];
            acc4.x += wj * ew.x * x.x;
            acc4.y += wj * ew.y * x.y;
            acc4.z += wj * ew.z * x.z;
            acc4.w += wj * ew.w * x.w;
        }
    }
    // combine the 4 sub-group partials
#pragma unroll
    for (int o = 16; o <= 32; o <<= 1) {
        acc4.x += __shfl_xor(acc4.x, o, 64);
        acc4.y += __shfl_xor(acc4.y, o, 64);
        acc4.z += __shfl_xor(acc4.z, o, 64);
        acc4.w += __shfl_xor(acc4.w, o, 64);
    }

    float cdeg = (float)max(deg, 1);
    float4 v = make_float4(acc4.x / cdeg, acc4.y / cdeg, acc4.z / cdeg, acc4.w / cdeg);
    float ss = v.x * v.x + v.y * v.y + v.z * v.z + v.w * v.w;
#pragma unroll
    for (int o = 1; o <= 8; o <<= 1) ss += __shfl_xor(ss, o, 64);
    float rinv = 1.0f / fmaxf(sqrtf(ss), 1e-12f);
    v.x *= rinv; v.y *= rinv; v.z *= rinv; v.w *= rinv;

    if (sub == 0) {
        ((float4*)aggNew)[(size_t)h * 16 + q] = v;
        float4 kgv = ((float4*)kg)[(size_t)h * 16 + q];
        float4 ev = ((const float4*)ent)[(size_t)h * 16 + q];
        kgv.x += v.x + ev.x; kgv.y += v.y + ev.y;
        kgv.z += v.z + ev.z; kgv.w += v.w + ev.w;
        ((float4*)kg)[(size_t)h * 16 + q] = kgv;
    }
}

extern "C" void kernel_launch(void* const* d_in, const int* in_sizes, int n_in,
                              void* d_out, int out_size, void* d_ws, size_t ws_size,
                              hipStream_t stream) {
    const float* ent  = (const float*)d_in[0];
    const float* eemb = (const float*)d_in[1];
    const float* qw   = (const float*)d_in[2];
    const float* kw   = (const float*)d_in[3];
    const int* eidx  = (const int*)d_in[4];
    const int* etype = (const int*)d_in[5];

    const int N = in_sizes[0] / EMB;
    const int R = in_sizes[1] / EMB;
    const int E = in_sizes[5];
    const int* head = eidx;
    const int* tail = eidx + E;

    float* kg = (float*)d_out;

    // workspace layout (spair first to keep 8-byte alignment)
    float* agg_a = (float*)d_ws;                 // N*EMB
    float* agg_b = agg_a + (size_t)N * EMB;      // N*EMB
    float* Qb    = agg_b + (size_t)N * EMB;      // N*EMB
    float* att   = Qb    + (size_t)N * EMB;      // E
    int2* spair  = (int2*)(att + E);             // E int2 (8-B aligned: 3*N*EMB+E even)
    int* offsets = (int*)(spair + E);            // N+1
    int* deg     = offsets + (N + 1);            // N
    int* cursor  = deg + N;                      // N
    int* bsum    = cursor + N;                   // up to 1024

    const int NT = 256;
    const int WPB = NT / 64;
    const int nb = (N + 1023) / 1024;

    // one-time: init + CSR build
    init_kernel<<<(N * EMB / 4 + NT - 1) / NT, NT, 0, stream>>>((float4*)agg_a, (float4*)kg,
                                                                (const float4*)ent, N * EMB / 4);
    hipMemsetAsync(deg, 0, (size_t)N * 4, stream);
    hipMemsetAsync(cursor, 0, (size_t)N * 4, stream);
    hist_kernel<<<(E + NT - 1) / NT, NT, 0, stream>>>(deg, head, E);
    scan_blocks<<<nb, NT, 0, stream>>>(deg, offsets, bsum, N);
    scan_sums<<<1, 1, 0, stream>>>(bsum, offsets, nb, N, E);
    scan_add<<<(N + NT - 1) / NT, NT, 0, stream>>>(offsets, bsum, N);
    sort_scatter<<<(E + NT - 1) / NT, NT, 0, stream>>>(head, tail, etype, offsets, cursor,
                                                       spair, E);

    float* cur = agg_a;
    float* nxt = agg_b;
    for (int hop = 0; hop < 2; ++hop) {
        qproj_mfma_kernel<<<512, NT, 0, stream>>>(Qb, cur, qw, N);
        att_mfma_kernel<<<1024, NT, 0, stream>>>(att, cur, Qb, eemb, kw, spair, E);
        head_agg_kernel<<<(N + WPB - 1) / WPB, NT, 0, stream>>>(nxt, kg, att, cur, eemb, ent,
                                                                offsets, spair, N, R);
        float* tmp = cur; cur = nxt; nxt = tmp;
    }
}